// Round 7
// baseline (172.159 us; speedup 1.0000x reference)
//
#include <hip/hip_runtime.h>
#include <hip/hip_bf16.h>

// GAT layer: N=4096, F_IN=128, F_OUT=64, HEADS=4.
// R18: gat_main ≈ 39us, still latency-bound at 16 waves/CU (grid 512 x 512thr
// = 2 blocks/CU caps occupancy at 50%). This round: (1) 1024-thr blocks
// (16 waves = 8 col-groups x 2 row-groups per 256-col chunk) -> 32 waves/CU
// = 100% occupancy, requires VGPR<=64 via __launch_bounds__(1024,8);
// (2) ALL LDS staging via global_load_lds width=16 (H panel + bits + ed/ed2):
// deletes every staging VGPR and ds_write, making the 64-clamp feasible
// (R13 spilled because the clamp was below genuine need; here need shrinks).
// Swizzled H layout preserved by PRE-SWIZZLING the global source column
// (linear LDS dest + inverse-swizzled source + swizzled read).
// SPILL WATCH: if hbm_bytes >> 13MB, the clamp spilled -> revert to R17.
// Kernels: pack_bits -> gat_prep -> gat_main (fused) -> gat_fin (tiny).

#define NN 4096
#define FIN 128
#define FOUT 64
#define NH 4

typedef __attribute__((ext_vector_type(8))) short bf16x8;
typedef __attribute__((ext_vector_type(4))) float f32x4;
typedef __attribute__((ext_vector_type(4))) unsigned int u32x4;

__device__ __forceinline__ unsigned short f32_bf16(float f) {
    unsigned u = __builtin_bit_cast(unsigned, f);
    u += 0x7fffu + ((u >> 16) & 1u);          // round-to-nearest-even
    return (unsigned short)(u >> 16);
}

__device__ __forceinline__ void gload16(const void* g, void* l) {
    __builtin_amdgcn_global_load_lds(
        (const __attribute__((address_space(1))) unsigned*)g,
        (__attribute__((address_space(3))) unsigned*)l, 16, 0, 0);
}

// ---------------- Kernel 0: pack A (int32 0/1) into bitmask ----------------
__global__ __launch_bounds__(256) void pack_bits(
    const int* __restrict__ A, unsigned long long* __restrict__ Abits)
{
    const int row  = blockIdx.x;
    const int lane = threadIdx.x & 63;
    const int wv   = threadIdx.x >> 6;
    const int* arow = A + (size_t)row * NN;
    #pragma unroll 4
    for (int c = 0; c < 16; ++c) {
        const int col = c * 256 + wv * 64 + lane;
        unsigned long long m = __ballot(__builtin_nontemporal_load(&arow[col]) > 0);
        if (lane == 0) Abits[(size_t)row * 64 + c * 4 + wv] = m;
    }
}

// ---------------- Kernel 1: prep ----------------
__global__ __launch_bounds__(256) void gat_prep(
    const float* __restrict__ X, const float* __restrict__ W,
    const float* __restrict__ b, const float* __restrict__ att,
    unsigned short* __restrict__ HbfT, float* __restrict__ Hrow,
    float* __restrict__ s_out, float* __restrict__ d_out,
    float* __restrict__ es_g, float* __restrict__ es2_g,
    float* __restrict__ ed_g, float* __restrict__ ed2_g)
{
    const int rb = blockIdx.x;           // 0..127
    const int h  = blockIdx.y;           // 0..3
    const int n0 = rb * 32;
    const int t  = threadIdx.x;          // 0..255

    __shared__ float Xl[32][132];
    __shared__ float Wt[128][68];

    for (int g = t; g < 32 * 32; g += 256) {
        int row = g >> 5, c4 = g & 31;
        float4 v = *(const float4*)&X[(size_t)(n0 + row) * FIN + c4 * 4];
        *(float4*)&Xl[row][c4 * 4] = v;
    }
    for (int g = t; g < 64 * 32; g += 256) {
        int o = g >> 5, c4 = g & 31;
        float4 v = *(const float4*)&W[((size_t)h * FOUT + o) * FIN + c4 * 4];
        Wt[c4 * 4 + 0][o] = v.x; Wt[c4 * 4 + 1][o] = v.y;
        Wt[c4 * 4 + 2][o] = v.z; Wt[c4 * 4 + 3][o] = v.w;
    }
    __syncthreads();

    const int rg = t >> 4;               // rows rg*2 .. rg*2+1
    const int og = t & 15;               // cols og*4 .. og*4+3
    float acc[2][4] = {};

    #pragma unroll 4
    for (int f4 = 0; f4 < 32; ++f4) {
        float xv[2][4], wv[4][4];
        #pragma unroll
        for (int i = 0; i < 2; ++i) {
            float4 tmp = *(const float4*)&Xl[rg * 2 + i][f4 * 4];
            xv[i][0] = tmp.x; xv[i][1] = tmp.y; xv[i][2] = tmp.z; xv[i][3] = tmp.w;
        }
        #pragma unroll
        for (int k = 0; k < 4; ++k) {
            float4 tmp = *(const float4*)&Wt[f4 * 4 + k][og * 4];
            wv[k][0] = tmp.x; wv[k][1] = tmp.y; wv[k][2] = tmp.z; wv[k][3] = tmp.w;
        }
        #pragma unroll
        for (int i = 0; i < 2; ++i)
            #pragma unroll
            for (int k = 0; k < 4; ++k)
                #pragma unroll
                for (int jj = 0; jj < 4; ++jj)
                    acc[i][jj] = fmaf(xv[i][k], wv[k][jj], acc[i][jj]);
    }

    float bb[4], as_[4], ad_[4];
    #pragma unroll
    for (int jj = 0; jj < 4; ++jj) {
        bb[jj]  = b[h * FOUT + og * 4 + jj];
        as_[jj] = att[h * 2 * FOUT + og * 4 + jj];
        ad_[jj] = att[h * 2 * FOUT + FOUT + og * 4 + jj];
    }
    #pragma unroll
    for (int i = 0; i < 2; ++i)
        #pragma unroll
        for (int jj = 0; jj < 4; ++jj)
            acc[i][jj] += bb[jj];

    float sp[2] = {0.f, 0.f}, dp[2] = {0.f, 0.f};
    #pragma unroll
    for (int i = 0; i < 2; ++i)
        #pragma unroll
        for (int jj = 0; jj < 4; ++jj) {
            sp[i] = fmaf(acc[i][jj], as_[jj], sp[i]);
            dp[i] = fmaf(acc[i][jj], ad_[jj], dp[i]);
        }
    #pragma unroll
    for (int off = 1; off < 16; off <<= 1) {
        #pragma unroll
        for (int i = 0; i < 2; ++i) {
            sp[i] += __shfl_xor(sp[i], off);
            dp[i] += __shfl_xor(dp[i], off);
        }
    }
    if (og == 0) {
        #pragma unroll
        for (int i = 0; i < 2; ++i) {
            int nn = n0 + rg * 2 + i;
            s_out[h * NN + nn]  = sp[i];
            d_out[h * NN + nn]  = dp[i];
            es_g [h * NN + nn]  = __expf(sp[i]);
            es2_g[h * NN + nn]  = __expf(0.01f * sp[i]);
            ed_g [h * NN + nn]  = __expf(dp[i]);
            ed2_g[h * NN + nn]  = __expf(0.01f * dp[i]);
        }
    }

    #pragma unroll
    for (int i = 0; i < 2; ++i) {
        float4 v = make_float4(acc[i][0], acc[i][1], acc[i][2], acc[i][3]);
        *(float4*)&Hrow[((size_t)h * NN + n0 + rg * 2 + i) * FOUT + og * 4] = v;
    }
    #pragma unroll
    for (int jj = 0; jj < 4; ++jj) {
        int o = og * 4 + jj;
        ushort2 p;
        p.x = f32_bf16(acc[0][jj]);
        p.y = f32_bf16(acc[1][jj]);
        *(ushort2*)&HbfT[((size_t)h * FOUT + o) * NN + n0 + rg * 2] = p;
    }
}

// ---------------- Kernel 2: fused masked softmax-aggregate ------------------
// Grid 512 x 1024thr (16 waves, 2 blocks/CU = 32 waves/CU). id -> h = id&3,
// tile = id>>2 (32 rows). Wave w: rg = w&1 (16 rows), kg = w>>1 (one 32-col
// group of each 256-col chunk). 16 chunks, double-buffered LDS, all staging
// via global_load_lds (H swizzle preserved by pre-swizzled source columns).
// Epilogue: 8-way kg reduction in LDS (aliases H), fused normalize + store.
struct SMem {
    union {
        __align__(16) unsigned short H[2][64][256];  // 64 KB dbuf
        struct {
            float red[7][2][16][68];                 // 59.5 KB (pad 68)
            float redl[7][2][16];
        } fin;
    };
    unsigned bits[2][32][8];                         // 2 KB (gload: linear)
    float ed [2][256];                               // 2 KB
    float ed2[2][256];                               // 2 KB
};

__global__ __launch_bounds__(1024, 8) void gat_main(
    const unsigned* __restrict__ Abits, const unsigned short* __restrict__ HbfT,
    const float* __restrict__ s_g, const float* __restrict__ d_g,
    const float* __restrict__ es_g, const float* __restrict__ es2_g,
    const float* __restrict__ ed_g, const float* __restrict__ ed2_g,
    const float* __restrict__ Hrow, float* __restrict__ outH)
{
    const int id   = blockIdx.x;         // 0..511
    const int h    = id & 3;
    const int tile = id >> 2;            // 0..127
    const int n0   = tile * 32;
    const int tid  = threadIdx.x;        // 0..1023
    const int w    = tid >> 6;           // wave 0..15
    const int lane = tid & 63;
    const int r    = lane & 15;          // A row within 16-row group / C col
    const int q    = lane >> 4;          // quad
    const int qs   = q * 8;
    const int rg   = w & 1;              // row group (16 rows)
    const int kg   = w >> 1;             // col group 0..7 (32 cols of chunk)

    __shared__ SMem sm;                  // ~70 KB -> 2 blocks/CU

    const int nrow = n0 + rg * 16 + r;
    const float es  = es_g [h * NN + nrow];
    const float es2 = es2_g[h * NN + nrow];

    // swizzled 16B-block index for B-fragment reads (constant per thread)
    const int cb   = kg * 4 + q;                       // 0..31
    const int sblk = (((cb & 15) ^ r) | (cb & 16));

    // ---- gload_lds source addresses (pre-swizzled global columns) ----
    // H: wave w stages rows 4w+{0,1} (instr A) and 4w+{2,3} (instr B).
    const int rowA = 4 * w + (lane >> 5);
    const int rowB = rowA + 2;
    const int blk  = lane & 31;
    const int gbA  = (((blk & 15) ^ (rowA & 15)) | (blk & 16));
    const int gbB  = (((blk & 15) ^ (rowB & 15)) | (blk & 16));
    const unsigned short* gHA = HbfT + ((size_t)(h * FOUT) + rowA) * NN + gbA * 8;
    const unsigned short* gHB = HbfT + ((size_t)(h * FOUT) + rowB) * NN + gbB * 8;
    // bits (wave 0): 32 rows x 8 u32 per chunk = 1 KB (lane covers 4 words)
    const unsigned* gBits = Abits + (size_t)(n0 + (lane >> 1)) * 128 + (lane & 1) * 4;
    // ed/ed2 (waves 1/2): 256 floats per chunk = 1 KB
    const float* gEd  = ed_g  + (size_t)h * NN + lane * 4;
    const float* gEd2 = ed2_g + (size_t)h * NN + lane * 4;

    bf16x8 ones;
    #pragma unroll
    for (int i = 0; i < 8; ++i) ones[i] = (short)0x3F80;   // bf16 1.0

    f32x4 acc0 = {0,0,0,0}, acc1 = {0,0,0,0}, acc2 = {0,0,0,0},
          acc3 = {0,0,0,0}, accl = {0,0,0,0};

    // ---- prologue: stage chunk 0 into buffer 0 (async DMA) ----
    gload16(gHA, &sm.H[0][4 * w][0]);
    gload16(gHB, &sm.H[0][4 * w + 2][0]);
    if      (w == 0) gload16(gBits, &sm.bits[0][0][0]);
    else if (w == 1) gload16(gEd,   &sm.ed [0][0]);
    else if (w == 2) gload16(gEd2,  &sm.ed2[0][0]);
    __syncthreads();                     // vmcnt(0) drain + barrier

    #pragma unroll 2
    for (int ch = 0; ch < 16; ++ch) {
        const int buf = ch & 1;

        // issue next chunk's DMA (in flight across this chunk's compute)
        if (ch < 15) {
            const int nb = buf ^ 1;
            gload16(gHA + (ch + 1) * 256, &sm.H[nb][4 * w][0]);
            gload16(gHB + (ch + 1) * 256, &sm.H[nb][4 * w + 2][0]);
            if      (w == 0) gload16(gBits + (ch + 1) * 8,   &sm.bits[nb][0][0]);
            else if (w == 1) gload16(gEd   + (ch + 1) * 256, &sm.ed [nb][0]);
            else if (w == 2) gload16(gEd2  + (ch + 1) * 256, &sm.ed2[nb][0]);
        }

        // ---- edge weights for (16 rows x 32 cols), inputs LDS-resident ----
        const unsigned bits8 = sm.bits[buf][rg * 16 + r][kg] >> qs;
        const float4 e0 = *(const float4*)&sm.ed [buf][kg * 32 + qs];
        const float4 e1 = *(const float4*)&sm.ed [buf][kg * 32 + qs + 4];
        const float4 g0 = *(const float4*)&sm.ed2[buf][kg * 32 + qs];
        const float4 g1 = *(const float4*)&sm.ed2[buf][kg * 32 + qs + 4];
        const float edv [8] = {e0.x, e0.y, e0.z, e0.w, e1.x, e1.y, e1.z, e1.w};
        const float ed2v[8] = {g0.x, g0.y, g0.z, g0.w, g1.x, g1.y, g1.z, g1.w};

        u32x4 afu;
        #pragma unroll
        for (int p = 0; p < 4; ++p) {
            const int j0 = 2 * p, j1 = 2 * p + 1;
            float wa = (bits8 & (1u << j0))
                     ? fmaxf(es * edv[j0], es2 * ed2v[j0]) : 0.0f;
            float wb = (bits8 & (1u << j1))
                     ? fmaxf(es * edv[j1], es2 * ed2v[j1]) : 0.0f;
            __hip_bfloat162 pk = __float22bfloat162_rn(make_float2(wa, wb));
            unsigned u;
            __builtin_memcpy(&u, &pk, sizeof(u));   // v_cvt_pk path
            afu[p] = u;
        }
        const bf16x8 af = __builtin_bit_cast(bf16x8, afu);

        // B fragments from swizzled LDS
        const bf16x8 b0 = *(const bf16x8*)&sm.H[buf][r     ][sblk * 8];
        const bf16x8 b1 = *(const bf16x8*)&sm.H[buf][r + 16][sblk * 8];
        const bf16x8 b2 = *(const bf16x8*)&sm.H[buf][r + 32][sblk * 8];
        const bf16x8 b3 = *(const bf16x8*)&sm.H[buf][r + 48][sblk * 8];

        acc0 = __builtin_amdgcn_mfma_f32_16x16x32_bf16(af, b0,   acc0, 0, 0, 0);
        acc1 = __builtin_amdgcn_mfma_f32_16x16x32_bf16(af, b1,   acc1, 0, 0, 0);
        acc2 = __builtin_amdgcn_mfma_f32_16x16x32_bf16(af, b2,   acc2, 0, 0, 0);
        acc3 = __builtin_amdgcn_mfma_f32_16x16x32_bf16(af, b3,   acc3, 0, 0, 0);
        accl = __builtin_amdgcn_mfma_f32_16x16x32_bf16(af, ones, accl, 0, 0, 0);

        __syncthreads();                 // drains next-chunk DMA + barrier
    }

    // ---- kg-reduction: kg 1..7 dump to LDS (aliases H), kg 0 accumulates ----
    if (kg > 0) {
        #pragma unroll
        for (int reg = 0; reg < 4; ++reg) {
            const int rr = q * 4 + reg;
            sm.fin.red[kg - 1][rg][rr][ 0 + r] = acc0[reg];
            sm.fin.red[kg - 1][rg][rr][16 + r] = acc1[reg];
            sm.fin.red[kg - 1][rg][rr][32 + r] = acc2[reg];
            sm.fin.red[kg - 1][rg][rr][48 + r] = acc3[reg];
        }
        if (r == 0) {
            #pragma unroll
            for (int reg = 0; reg < 4; ++reg)
                sm.fin.redl[kg - 1][rg][q * 4 + reg] = accl[reg];
        }
    }
    __syncthreads();
    if (kg == 0) {
        #pragma unroll
        for (int kk = 0; kk < 7; ++kk) {
            #pragma unroll
            for (int reg = 0; reg < 4; ++reg) {
                const int rr = q * 4 + reg;
                acc0[reg] += sm.fin.red[kk][rg][rr][ 0 + r];
                acc1[reg] += sm.fin.red[kk][rg][rr][16 + r];
                acc2[reg] += sm.fin.red[kk][rg][rr][32 + r];
                acc3[reg] += sm.fin.red[kk][rg][rr][48 + r];
                accl[reg] += sm.fin.redl[kk][rg][rr];
            }
        }
        // ---- fused normalize + diagonal + store per-head output ----
        #pragma unroll
        for (int reg = 0; reg < 4; ++reg) {
            const int rr  = q * 4 + reg;
            const int nn2 = n0 + rg * 16 + rr;
            const float tt = s_g[h * NN + nn2] + d_g[h * NN + nn2];
            const float wd = __expf(fmaxf(tt, 0.01f * tt));
            const float inv = 0.25f / (accl[reg] + wd);
            const float* hr = &Hrow[((size_t)h * NN + nn2) * FOUT];
            float*       ob = &outH[((size_t)h * NN + nn2) * FOUT];
            ob[ 0 + r] = (acc0[reg] + wd * hr[ 0 + r]) * inv;
            ob[16 + r] = (acc1[reg] + wd * hr[16 + r]) * inv;
            ob[32 + r] = (acc2[reg] + wd * hr[32 + r]) * inv;
            ob[48 + r] = (acc3[reg] + wd * hr[48 + r]) * inv;
        }
    }
}

// ---------------- Kernel 3: tiny finalize — sum 4 heads ----------------
__global__ __launch_bounds__(256) void gat_fin(
    const float* __restrict__ outH, float* __restrict__ out)
{
    const int i = blockIdx.x * 256 + threadIdx.x;    // 0..65535 float4s
    const f32x4* p = (const f32x4*)outH;
    f32x4 v0 = __builtin_nontemporal_load(p + i);
    f32x4 v1 = __builtin_nontemporal_load(p + i +  65536);
    f32x4 v2 = __builtin_nontemporal_load(p + i + 131072);
    f32x4 v3 = __builtin_nontemporal_load(p + i + 196608);
    f32x4 s = (v0 + v1) + (v2 + v3);
    *((f32x4*)out + i) = s;
}

extern "C" void kernel_launch(void* const* d_in, const int* in_sizes, int n_in,
                              void* d_out, int out_size, void* d_ws, size_t ws_size,
                              hipStream_t stream) {
    const float* X   = (const float*)d_in[0];
    const int*   A   = (const int*)  d_in[1];
    const float* W   = (const float*)d_in[2];
    const float* b   = (const float*)d_in[3];
    const float* att = (const float*)d_in[4];
    float* out = (float*)d_out;

    char* ws = (char*)d_ws;
    unsigned short* HbfT = (unsigned short*)ws;                    // 2 MB
    size_t off = (size_t)NH * FOUT * NN * 2;
    float* s_buf   = (float*)(ws + off);  off += (size_t)NH * NN * 4;
    float* d_buf   = (float*)(ws + off);  off += (size_t)NH * NN * 4;
    float* es_buf  = (float*)(ws + off);  off += (size_t)NH * NN * 4;
    float* es2_buf = (float*)(ws + off);  off += (size_t)NH * NN * 4;
    float* ed_buf  = (float*)(ws + off);  off += (size_t)NH * NN * 4;
    float* ed2_buf = (float*)(ws + off);  off += (size_t)NH * NN * 4;
    unsigned long long* Abits = (unsigned long long*)(ws + off);
    off += (size_t)NN * 64 * 8;                                         // 2 MB
    float* Hrow   = (float*)(ws + off);
    off += (size_t)NH * NN * FOUT * 4;                                  // 4 MB
    float* outH   = (float*)(ws + off);
    off += (size_t)NH * NN * FOUT * 4;                                  // 4 MB

    pack_bits<<<NN, 256, 0, stream>>>(A, Abits);
    gat_prep<<<dim3(128, 4), 256, 0, stream>>>(X, W, b, att, HbfT, Hrow,
                                               s_buf, d_buf,
                                               es_buf, es2_buf, ed_buf, ed2_buf);
    gat_main<<<512, 1024, 0, stream>>>((const unsigned*)Abits, HbfT,
                                       s_buf, d_buf,
                                       es_buf, es2_buf, ed_buf, ed2_buf,
                                       Hrow, outH);
    gat_fin<<<256, 256, 0, stream>>>(outH, out);
}

// Round 8
// 157.648 us; speedup vs baseline: 1.0920x; 1.0920x over previous
//
#include <hip/hip_runtime.h>
#include <hip/hip_bf16.h>

// GAT layer: N=4096, F_IN=128, F_OUT=64, HEADS=4.
// R19: R17 skeleton (512thr, launch_bounds(512,4)=128-VGPR budget -> NO
// spills; 16 chunks x 256 cols, dbuf LDS, 1 barrier/chunk) + R18's
// global_load_lds staging (verified swizzle: linear LDS dest + pre-swizzled
// global source + swizzled read). vs R17 this deletes the reg-staging
// round-trip: ~16 staging VGPRs + the ds_write block leave the per-chunk
// critical path; DMA issued at loop top lands during compute; the barrier's
// vmcnt(0) drain is exactly where the data is needed.
// R18 lesson (with R13): clamping VGPR below ~64 live regs spills -> never
// clamp below need. 1024-thr/32-wave occupancy is unreachable without
// spills; 16 waves/CU + short critical path is the operating point.
// Kernels: pack_bits -> gat_prep -> gat_main (fused) -> gat_fin (tiny).

#define NN 4096
#define FIN 128
#define FOUT 64
#define NH 4

typedef __attribute__((ext_vector_type(8))) short bf16x8;
typedef __attribute__((ext_vector_type(4))) float f32x4;
typedef __attribute__((ext_vector_type(4))) unsigned int u32x4;

__device__ __forceinline__ unsigned short f32_bf16(float f) {
    unsigned u = __builtin_bit_cast(unsigned, f);
    u += 0x7fffu + ((u >> 16) & 1u);          // round-to-nearest-even
    return (unsigned short)(u >> 16);
}

__device__ __forceinline__ void gload16(const void* g, void* l) {
    __builtin_amdgcn_global_load_lds(
        (const __attribute__((address_space(1))) unsigned*)g,
        (__attribute__((address_space(3))) unsigned*)l, 16, 0, 0);
}

// ---------------- Kernel 0: pack A (int32 0/1) into bitmask ----------------
__global__ __launch_bounds__(256) void pack_bits(
    const int* __restrict__ A, unsigned long long* __restrict__ Abits)
{
    const int row  = blockIdx.x;
    const int lane = threadIdx.x & 63;
    const int wv   = threadIdx.x >> 6;
    const int* arow = A + (size_t)row * NN;
    #pragma unroll 4
    for (int c = 0; c < 16; ++c) {
        const int col = c * 256 + wv * 64 + lane;
        unsigned long long m = __ballot(__builtin_nontemporal_load(&arow[col]) > 0);
        if (lane == 0) Abits[(size_t)row * 64 + c * 4 + wv] = m;
    }
}

// ---------------- Kernel 1: prep ----------------
__global__ __launch_bounds__(256) void gat_prep(
    const float* __restrict__ X, const float* __restrict__ W,
    const float* __restrict__ b, const float* __restrict__ att,
    unsigned short* __restrict__ HbfT, float* __restrict__ Hrow,
    float* __restrict__ s_out, float* __restrict__ d_out,
    float* __restrict__ es_g, float* __restrict__ es2_g,
    float* __restrict__ ed_g, float* __restrict__ ed2_g)
{
    const int rb = blockIdx.x;           // 0..127
    const int h  = blockIdx.y;           // 0..3
    const int n0 = rb * 32;
    const int t  = threadIdx.x;          // 0..255

    __shared__ float Xl[32][132];
    __shared__ float Wt[128][68];

    for (int g = t; g < 32 * 32; g += 256) {
        int row = g >> 5, c4 = g & 31;
        float4 v = *(const float4*)&X[(size_t)(n0 + row) * FIN + c4 * 4];
        *(float4*)&Xl[row][c4 * 4] = v;
    }
    for (int g = t; g < 64 * 32; g += 256) {
        int o = g >> 5, c4 = g & 31;
        float4 v = *(const float4*)&W[((size_t)h * FOUT + o) * FIN + c4 * 4];
        Wt[c4 * 4 + 0][o] = v.x; Wt[c4 * 4 + 1][o] = v.y;
        Wt[c4 * 4 + 2][o] = v.z; Wt[c4 * 4 + 3][o] = v.w;
    }
    __syncthreads();

    const int rg = t >> 4;               // rows rg*2 .. rg*2+1
    const int og = t & 15;               // cols og*4 .. og*4+3
    float acc[2][4] = {};

    #pragma unroll 4
    for (int f4 = 0; f4 < 32; ++f4) {
        float xv[2][4], wv[4][4];
        #pragma unroll
        for (int i = 0; i < 2; ++i) {
            float4 tmp = *(const float4*)&Xl[rg * 2 + i][f4 * 4];
            xv[i][0] = tmp.x; xv[i][1] = tmp.y; xv[i][2] = tmp.z; xv[i][3] = tmp.w;
        }
        #pragma unroll
        for (int k = 0; k < 4; ++k) {
            float4 tmp = *(const float4*)&Wt[f4 * 4 + k][og * 4];
            wv[k][0] = tmp.x; wv[k][1] = tmp.y; wv[k][2] = tmp.z; wv[k][3] = tmp.w;
        }
        #pragma unroll
        for (int i = 0; i < 2; ++i)
            #pragma unroll
            for (int k = 0; k < 4; ++k)
                #pragma unroll
                for (int jj = 0; jj < 4; ++jj)
                    acc[i][jj] = fmaf(xv[i][k], wv[k][jj], acc[i][jj]);
    }

    float bb[4], as_[4], ad_[4];
    #pragma unroll
    for (int jj = 0; jj < 4; ++jj) {
        bb[jj]  = b[h * FOUT + og * 4 + jj];
        as_[jj] = att[h * 2 * FOUT + og * 4 + jj];
        ad_[jj] = att[h * 2 * FOUT + FOUT + og * 4 + jj];
    }
    #pragma unroll
    for (int i = 0; i < 2; ++i)
        #pragma unroll
        for (int jj = 0; jj < 4; ++jj)
            acc[i][jj] += bb[jj];

    float sp[2] = {0.f, 0.f}, dp[2] = {0.f, 0.f};
    #pragma unroll
    for (int i = 0; i < 2; ++i)
        #pragma unroll
        for (int jj = 0; jj < 4; ++jj) {
            sp[i] = fmaf(acc[i][jj], as_[jj], sp[i]);
            dp[i] = fmaf(acc[i][jj], ad_[jj], dp[i]);
        }
    #pragma unroll
    for (int off = 1; off < 16; off <<= 1) {
        #pragma unroll
        for (int i = 0; i < 2; ++i) {
            sp[i] += __shfl_xor(sp[i], off);
            dp[i] += __shfl_xor(dp[i], off);
        }
    }
    if (og == 0) {
        #pragma unroll
        for (int i = 0; i < 2; ++i) {
            int nn = n0 + rg * 2 + i;
            s_out[h * NN + nn]  = sp[i];
            d_out[h * NN + nn]  = dp[i];
            es_g [h * NN + nn]  = __expf(sp[i]);
            es2_g[h * NN + nn]  = __expf(0.01f * sp[i]);
            ed_g [h * NN + nn]  = __expf(dp[i]);
            ed2_g[h * NN + nn]  = __expf(0.01f * dp[i]);
        }
    }

    #pragma unroll
    for (int i = 0; i < 2; ++i) {
        float4 v = make_float4(acc[i][0], acc[i][1], acc[i][2], acc[i][3]);
        *(float4*)&Hrow[((size_t)h * NN + n0 + rg * 2 + i) * FOUT + og * 4] = v;
    }
    #pragma unroll
    for (int jj = 0; jj < 4; ++jj) {
        int o = og * 4 + jj;
        ushort2 p;
        p.x = f32_bf16(acc[0][jj]);
        p.y = f32_bf16(acc[1][jj]);
        *(ushort2*)&HbfT[((size_t)h * FOUT + o) * NN + n0 + rg * 2] = p;
    }
}

// ---------------- Kernel 2: fused masked softmax-aggregate ------------------
// Grid 512 x 512thr. id -> h = id&3, tile = id>>2 (32 rows). 8 waves:
// rg = w&1 (16 rows), kg = w>>1; wave kg computes 32-col groups {kg, kg+4}
// of each 256-col chunk (16 chunks). ALL staging via global_load_lds DMA
// (H pre-swizzled source; bits/ed/ed2 linear), issued at loop top, landing
// during compute, drained by the barrier's vmcnt(0). Epilogue: LDS
// K-reduction (aliases H), fused normalize + diagonal + store.
struct SMem {
    union {
        __align__(16) unsigned short H[2][64][256];  // 64 KB dbuf
        struct {
            float red[6][16][68];                    // 25.5 KB (pad 68)
            float redl[6][16];
        } fin;
    };
    unsigned bits[2][32][8];                         // 2 KB (gload: linear)
    float ed [2][256];                               // 2 KB
    float ed2[2][256];                               // 2 KB
};

__global__ __launch_bounds__(512, 4) void gat_main(
    const unsigned* __restrict__ Abits, const unsigned short* __restrict__ HbfT,
    const float* __restrict__ s_g, const float* __restrict__ d_g,
    const float* __restrict__ es_g, const float* __restrict__ es2_g,
    const float* __restrict__ ed_g, const float* __restrict__ ed2_g,
    const float* __restrict__ Hrow, float* __restrict__ outH)
{
    const int id   = blockIdx.x;         // 0..511
    const int h    = id & 3;
    const int tile = id >> 2;            // 0..127
    const int n0   = tile * 32;
    const int tid  = threadIdx.x;        // 0..511
    const int w    = tid >> 6;           // wave 0..7
    const int lane = tid & 63;
    const int r    = lane & 15;          // A row within 16-row group / C col
    const int q    = lane >> 4;          // quad
    const int qs   = q * 8;
    const int rg   = w & 1;              // row group
    const int kg   = w >> 1;             // col-group pair {kg, kg+4}

    __shared__ SMem sm;                  // ~70 KB -> 2 blocks/CU

    const int nrow = n0 + rg * 16 + r;
    const float es  = es_g [h * NN + nrow];
    const float es2 = es2_g[h * NN + nrow];

    // swizzled 16B-block index for B-fragment reads (constant per thread)
    const int bb = ((kg * 4 + q) ^ r) & 15;

    // ---- gload_lds sources (H pre-swizzled; bits/ed/ed2 linear) ----
    // H: wave w stages rows [8w, 8w+8) via 4 DMA instrs, 2 rows each.
    const int blk = lane & 31;
    const unsigned short* gH[4];
    #pragma unroll
    for (int i = 0; i < 4; ++i) {
        const int row = 8 * w + 2 * i + (lane >> 5);
        const int gb  = ((blk & 15) ^ (row & 15)) | (blk & 16);
        gH[i] = HbfT + ((size_t)(h * FOUT) + row) * NN + gb * 8;
    }
    // bits (wave 0): 32 rows x 8 u32 per chunk = 1 KB, lane -> (row, 4 words)
    const unsigned* gBits = Abits + (size_t)(n0 + (lane >> 1)) * 128 + (lane & 1) * 4;
    // ed / ed2 (waves 1 / 2): 256 floats per chunk = 1 KB
    const float* gEd  = ed_g  + (size_t)h * NN + lane * 4;
    const float* gEd2 = ed2_g + (size_t)h * NN + lane * 4;

    bf16x8 ones;
    #pragma unroll
    for (int i = 0; i < 8; ++i) ones[i] = (short)0x3F80;   // bf16 1.0

    f32x4 acc0 = {0,0,0,0}, acc1 = {0,0,0,0}, acc2 = {0,0,0,0},
          acc3 = {0,0,0,0}, accl = {0,0,0,0};

    // ---- prologue: stage chunk 0 into buffer 0 (async DMA) ----
    {
        unsigned short* hw = &sm.H[0][8 * w][0];
        gload16(gH[0], hw);
        gload16(gH[1], hw +  512);
        gload16(gH[2], hw + 1024);
        gload16(gH[3], hw + 1536);
        if      (w == 0) gload16(gBits, &sm.bits[0][0][0]);
        else if (w == 1) gload16(gEd,   &sm.ed [0][0]);
        else if (w == 2) gload16(gEd2,  &sm.ed2[0][0]);
    }
    __syncthreads();                     // vmcnt(0) drain + barrier

    #pragma unroll 2
    for (int ch = 0; ch < 16; ++ch) {
        const int buf = ch & 1;

        // issue next chunk's DMA (lands during this chunk's compute)
        if (ch < 15) {
            const int nb   = buf ^ 1;
            const int coff = (ch + 1) * 256;
            unsigned short* hw = &sm.H[nb][8 * w][0];
            gload16(gH[0] + coff, hw);
            gload16(gH[1] + coff, hw +  512);
            gload16(gH[2] + coff, hw + 1024);
            gload16(gH[3] + coff, hw + 1536);
            if      (w == 0) gload16(gBits + (ch + 1) * 8, &sm.bits[nb][0][0]);
            else if (w == 1) gload16(gEd  + coff, &sm.ed [nb][0]);
            else if (w == 2) gload16(gEd2 + coff, &sm.ed2[nb][0]);
        }

        // ---- group a: cols [kg*32, +32) of this chunk ----
        {
            const unsigned bits8 = sm.bits[buf][rg * 16 + r][kg] >> qs;
            const float4 e0 = *(const float4*)&sm.ed [buf][kg * 32 + qs];
            const float4 e1 = *(const float4*)&sm.ed [buf][kg * 32 + qs + 4];
            const float4 g0 = *(const float4*)&sm.ed2[buf][kg * 32 + qs];
            const float4 g1 = *(const float4*)&sm.ed2[buf][kg * 32 + qs + 4];
            const float edv [8] = {e0.x, e0.y, e0.z, e0.w, e1.x, e1.y, e1.z, e1.w};
            const float ed2v[8] = {g0.x, g0.y, g0.z, g0.w, g1.x, g1.y, g1.z, g1.w};
            u32x4 afu;
            #pragma unroll
            for (int p = 0; p < 4; ++p) {
                const int j0 = 2 * p, j1 = 2 * p + 1;
                float wa = (bits8 & (1u << j0))
                         ? fmaxf(es * edv[j0], es2 * ed2v[j0]) : 0.0f;
                float wb = (bits8 & (1u << j1))
                         ? fmaxf(es * edv[j1], es2 * ed2v[j1]) : 0.0f;
                __hip_bfloat162 pk = __float22bfloat162_rn(make_float2(wa, wb));
                unsigned u;
                __builtin_memcpy(&u, &pk, sizeof(u));
                afu[p] = u;
            }
            const bf16x8 af = __builtin_bit_cast(bf16x8, afu);

            const bf16x8 b0 = *(const bf16x8*)&sm.H[buf][r     ][bb * 8];
            const bf16x8 b1 = *(const bf16x8*)&sm.H[buf][r + 16][bb * 8];
            const bf16x8 b2 = *(const bf16x8*)&sm.H[buf][r + 32][bb * 8];
            const bf16x8 b3 = *(const bf16x8*)&sm.H[buf][r + 48][bb * 8];

            acc0 = __builtin_amdgcn_mfma_f32_16x16x32_bf16(af, b0,   acc0, 0, 0, 0);
            acc1 = __builtin_amdgcn_mfma_f32_16x16x32_bf16(af, b1,   acc1, 0, 0, 0);
            acc2 = __builtin_amdgcn_mfma_f32_16x16x32_bf16(af, b2,   acc2, 0, 0, 0);
            acc3 = __builtin_amdgcn_mfma_f32_16x16x32_bf16(af, b3,   acc3, 0, 0, 0);
            accl = __builtin_amdgcn_mfma_f32_16x16x32_bf16(af, ones, accl, 0, 0, 0);
        }

        // ---- group b: cols [128 + kg*32, +32) of this chunk ----
        {
            const unsigned bits8 = sm.bits[buf][rg * 16 + r][kg + 4] >> qs;
            const float4 e0 = *(const float4*)&sm.ed [buf][128 + kg * 32 + qs];
            const float4 e1 = *(const float4*)&sm.ed [buf][128 + kg * 32 + qs + 4];
            const float4 g0 = *(const float4*)&sm.ed2[buf][128 + kg * 32 + qs];
            const float4 g1 = *(const float4*)&sm.ed2[buf][128 + kg * 32 + qs + 4];
            const float edv [8] = {e0.x, e0.y, e0.z, e0.w, e1.x, e1.y, e1.z, e1.w};
            const float ed2v[8] = {g0.x, g0.y, g0.z, g0.w, g1.x, g1.y, g1.z, g1.w};
            u32x4 afu;
            #pragma unroll
            for (int p = 0; p < 4; ++p) {
                const int j0 = 2 * p, j1 = 2 * p + 1;
                float wa = (bits8 & (1u << j0))
                         ? fmaxf(es * edv[j0], es2 * ed2v[j0]) : 0.0f;
                float wb = (bits8 & (1u << j1))
                         ? fmaxf(es * edv[j1], es2 * ed2v[j1]) : 0.0f;
                __hip_bfloat162 pk = __float22bfloat162_rn(make_float2(wa, wb));
                unsigned u;
                __builtin_memcpy(&u, &pk, sizeof(u));
                afu[p] = u;
            }
            const bf16x8 af = __builtin_bit_cast(bf16x8, afu);

            const bf16x8 b0 = *(const bf16x8*)&sm.H[buf][r     ][128 + bb * 8];
            const bf16x8 b1 = *(const bf16x8*)&sm.H[buf][r + 16][128 + bb * 8];
            const bf16x8 b2 = *(const bf16x8*)&sm.H[buf][r + 32][128 + bb * 8];
            const bf16x8 b3 = *(const bf16x8*)&sm.H[buf][r + 48][128 + bb * 8];

            acc0 = __builtin_amdgcn_mfma_f32_16x16x32_bf16(af, b0,   acc0, 0, 0, 0);
            acc1 = __builtin_amdgcn_mfma_f32_16x16x32_bf16(af, b1,   acc1, 0, 0, 0);
            acc2 = __builtin_amdgcn_mfma_f32_16x16x32_bf16(af, b2,   acc2, 0, 0, 0);
            acc3 = __builtin_amdgcn_mfma_f32_16x16x32_bf16(af, b3,   acc3, 0, 0, 0);
            accl = __builtin_amdgcn_mfma_f32_16x16x32_bf16(af, ones, accl, 0, 0, 0);
        }

        __syncthreads();                 // drains next-chunk DMA + barrier
    }

    // ---- K-partial reduction: kg 1..3 dump to LDS, kg 0 accumulates ----
    // (sm.fin aliases sm.H — all stage reads completed before last barrier)
    if (kg > 0) {
        const int widx = (kg - 1) * 2 + rg;
        #pragma unroll
        for (int reg = 0; reg < 4; ++reg) {
            const int rr = q * 4 + reg;
            sm.fin.red[widx][rr][ 0 + r] = acc0[reg];
            sm.fin.red[widx][rr][16 + r] = acc1[reg];
            sm.fin.red[widx][rr][32 + r] = acc2[reg];
            sm.fin.red[widx][rr][48 + r] = acc3[reg];
        }
        if (r == 0) {
            #pragma unroll
            for (int reg = 0; reg < 4; ++reg)
                sm.fin.redl[widx][q * 4 + reg] = accl[reg];
        }
    }
    __syncthreads();
    if (kg == 0) {
        #pragma unroll
        for (int kk = 0; kk < 3; ++kk) {
            const int widx = kk * 2 + rg;
            #pragma unroll
            for (int reg = 0; reg < 4; ++reg) {
                const int rr = q * 4 + reg;
                acc0[reg] += sm.fin.red[widx][rr][ 0 + r];
                acc1[reg] += sm.fin.red[widx][rr][16 + r];
                acc2[reg] += sm.fin.red[widx][rr][32 + r];
                acc3[reg] += sm.fin.red[widx][rr][48 + r];
                accl[reg] += sm.fin.redl[widx][rr];
            }
        }
        // ---- fused normalize + diagonal + store per-head output ----
        #pragma unroll
        for (int reg = 0; reg < 4; ++reg) {
            const int rr  = q * 4 + reg;
            const int nn2 = n0 + rg * 16 + rr;
            const float tt = s_g[h * NN + nn2] + d_g[h * NN + nn2];
            const float wd = __expf(fmaxf(tt, 0.01f * tt));
            const float inv = 0.25f / (accl[reg] + wd);
            const float* hr = &Hrow[((size_t)h * NN + nn2) * FOUT];
            float*       ob = &outH[((size_t)h * NN + nn2) * FOUT];
            ob[ 0 + r] = (acc0[reg] + wd * hr[ 0 + r]) * inv;
            ob[16 + r] = (acc1[reg] + wd * hr[16 + r]) * inv;
            ob[32 + r] = (acc2[reg] + wd * hr[32 + r]) * inv;
            ob[48 + r] = (acc3[reg] + wd * hr[48 + r]) * inv;
        }
    }
}

// ---------------- Kernel 3: tiny finalize — sum 4 heads ----------------
__global__ __launch_bounds__(256) void gat_fin(
    const float* __restrict__ outH, float* __restrict__ out)
{
    const int i = blockIdx.x * 256 + threadIdx.x;    // 0..65535 float4s
    const f32x4* p = (const f32x4*)outH;
    f32x4 v0 = __builtin_nontemporal_load(p + i);
    f32x4 v1 = __builtin_nontemporal_load(p + i +  65536);
    f32x4 v2 = __builtin_nontemporal_load(p + i + 131072);
    f32x4 v3 = __builtin_nontemporal_load(p + i + 196608);
    f32x4 s = (v0 + v1) + (v2 + v3);
    *((f32x4*)out + i) = s;
}

extern "C" void kernel_launch(void* const* d_in, const int* in_sizes, int n_in,
                              void* d_out, int out_size, void* d_ws, size_t ws_size,
                              hipStream_t stream) {
    const float* X   = (const float*)d_in[0];
    const int*   A   = (const int*)  d_in[1];
    const float* W   = (const float*)d_in[2];
    const float* b   = (const float*)d_in[3];
    const float* att = (const float*)d_in[4];
    float* out = (float*)d_out;

    char* ws = (char*)d_ws;
    unsigned short* HbfT = (unsigned short*)ws;                    // 2 MB
    size_t off = (size_t)NH * FOUT * NN * 2;
    float* s_buf   = (float*)(ws + off);  off += (size_t)NH * NN * 4;
    float* d_buf   = (float*)(ws + off);  off += (size_t)NH * NN * 4;
    float* es_buf  = (float*)(ws + off);  off += (size_t)NH * NN * 4;
    float* es2_buf = (float*)(ws + off);  off += (size_t)NH * NN * 4;
    float* ed_buf  = (float*)(ws + off);  off += (size_t)NH * NN * 4;
    float* ed2_buf = (float*)(ws + off);  off += (size_t)NH * NN * 4;
    unsigned long long* Abits = (unsigned long long*)(ws + off);
    off += (size_t)NN * 64 * 8;                                         // 2 MB
    float* Hrow   = (float*)(ws + off);
    off += (size_t)NH * NN * FOUT * 4;                                  // 4 MB
    float* outH   = (float*)(ws + off);
    off += (size_t)NH * NN * FOUT * 4;                                  // 4 MB

    pack_bits<<<NN, 256, 0, stream>>>(A, Abits);
    gat_prep<<<dim3(128, 4), 256, 0, stream>>>(X, W, b, att, HbfT, Hrow,
                                               s_buf, d_buf,
                                               es_buf, es2_buf, ed_buf, ed2_buf);
    gat_main<<<512, 512, 0, stream>>>((const unsigned*)Abits, HbfT,
                                      s_buf, d_buf,
                                      es_buf, es2_buf, ed_buf, ed2_buf,
                                      Hrow, outH);
    gat_fin<<<256, 256, 0, stream>>>(outH, out);
}